// Round 1
// baseline (304.498 us; speedup 1.0000x reference)
//
#include <hip/hip_runtime.h>
#include <hip/hip_bf16.h>

#define N_SRC   131072
#define N_DST   65536
#define N_EDGES 524288
#define D       128      // D_IN == D_OUT == 128

// ---------------------------------------------------------------------------
// Kernel 1: per-dst-row neighbor mean via binary search on sorted dst_idx.
// One block (128 threads) per dst row; thread j handles feature column j.
// No atomics: dst_idx is sorted, so each row owns a contiguous edge range.
// ---------------------------------------------------------------------------
__global__ __launch_bounds__(128) void neigh_kernel(
    const float* __restrict__ feat,
    const int*   __restrict__ src,
    const int*   __restrict__ dst,
    int n_edges,
    float* __restrict__ h_neigh)
{
    const int d = blockIdx.x;
    const int j = threadIdx.x;

    // lower_bound(dst, d)  — uniform across the block (no divergence)
    int lo = 0, hi = n_edges;
    while (lo < hi) { int m = (lo + hi) >> 1; if (dst[m] < d) lo = m + 1; else hi = m; }
    const int start = lo;
    // lower_bound(dst, d+1)
    hi = n_edges;
    while (lo < hi) { int m = (lo + hi) >> 1; if (dst[m] < d + 1) lo = m + 1; else hi = m; }
    const int end = lo;

    float sum = 0.0f;
    for (int e = start; e < end; ++e) {
        const int s = src[e];                      // uniform -> scalar load
        sum += feat[(size_t)s * D + j];            // coalesced across threads
    }
    const float deg = (float)(end - start);
    h_neigh[(size_t)d * D + j] = sum / fmaxf(deg, 1.0f);
}

// ---------------------------------------------------------------------------
// Kernel 2: out = feat[:N_DST] @ W_self + h_neigh @ W_neigh + (b_self+b_neigh)
// Tile: 64 rows x 128 cols per 256-thread block. K processed in chunks of 32,
// two phases (self / neigh). A-tile stored TRANSPOSED in LDS (As[k][r]) so the
// inner loop reads are ds_read_b128. B-tile row-major.
// Thread (tx,ty): tx=t&31 -> cols 4*tx..4*tx+3 ; ty=t>>5 -> rows ty*8..ty*8+7.
// ---------------------------------------------------------------------------
#define TM 64
#define KC 32

__global__ __launch_bounds__(256) void gemm_kernel(
    const float* __restrict__ feat,
    const float* __restrict__ h_neigh,
    const float* __restrict__ W_self,
    const float* __restrict__ W_neigh,
    const float* __restrict__ b_self,
    const float* __restrict__ b_neigh,
    float* __restrict__ out)
{
    __shared__ float As[KC][TM];    // transposed A tile: As[k][r]
    __shared__ float Bs[KC][D];     // B tile: Bs[k][j]

    const int t   = threadIdx.x;
    const int tx  = t & 31;
    const int ty  = t >> 5;
    const int row0 = blockIdx.x * TM;

    float acc[8][4];
    #pragma unroll
    for (int i = 0; i < 8; ++i)
        #pragma unroll
        for (int c = 0; c < 4; ++c) acc[i][c] = 0.0f;

    for (int phase = 0; phase < 2; ++phase) {
        const float* __restrict__ A = phase ? h_neigh : feat;
        const float* __restrict__ W = phase ? W_neigh : W_self;

        for (int kb = 0; kb < D; kb += KC) {
            __syncthreads();   // protect previous iteration's LDS reads

            // Load A tile (64 x 32 floats = 512 float4; 2 per thread),
            // scatter transposed into As[k][r].
            #pragma unroll
            for (int i = 0; i < 2; ++i) {
                const int f  = t + i * 256;        // 0..511
                const int r  = f >> 3;             // 0..63
                const int kc = (f & 7) * 4;        // 0,4,...,28
                const float4 v = *(const float4*)&A[(size_t)(row0 + r) * D + kb + kc];
                As[kc + 0][r] = v.x;
                As[kc + 1][r] = v.y;
                As[kc + 2][r] = v.z;
                As[kc + 3][r] = v.w;
            }
            // Load B tile (32 x 128 floats = 1024 float4; 4 per thread).
            #pragma unroll
            for (int i = 0; i < 4; ++i) {
                const int f  = t + i * 256;        // 0..1023
                const int kk = f >> 5;             // 0..31
                const int jc = (f & 31) * 4;
                *(float4*)&Bs[kk][jc] = *(const float4*)&W[(size_t)(kb + kk) * D + jc];
            }
            __syncthreads();

            #pragma unroll
            for (int k = 0; k < KC; ++k) {
                const float4 b  = *(const float4*)&Bs[k][tx * 4];
                const float4 a0 = *(const float4*)&As[k][ty * 8];       // rows ty*8..+3
                const float4 a1 = *(const float4*)&As[k][ty * 8 + 4];   // rows ty*8+4..+7
                const float av[8] = {a0.x, a0.y, a0.z, a0.w, a1.x, a1.y, a1.z, a1.w};
                const float bv[4] = {b.x, b.y, b.z, b.w};
                #pragma unroll
                for (int ri = 0; ri < 8; ++ri)
                    #pragma unroll
                    for (int c = 0; c < 4; ++c)
                        acc[ri][c] += av[ri] * bv[c];
            }
        }
    }

    // Epilogue: add biases, write out (coalesced float4).
    const float4 bs = *(const float4*)&b_self[tx * 4];
    const float4 bn = *(const float4*)&b_neigh[tx * 4];
    const float bias[4] = {bs.x + bn.x, bs.y + bn.y, bs.z + bn.z, bs.w + bn.w};

    #pragma unroll
    for (int ri = 0; ri < 8; ++ri) {
        const int r = row0 + ty * 8 + ri;
        float4 o;
        o.x = acc[ri][0] + bias[0];
        o.y = acc[ri][1] + bias[1];
        o.z = acc[ri][2] + bias[2];
        o.w = acc[ri][3] + bias[3];
        *(float4*)&out[(size_t)r * D + tx * 4] = o;
    }
}

// ---------------------------------------------------------------------------
extern "C" void kernel_launch(void* const* d_in, const int* in_sizes, int n_in,
                              void* d_out, int out_size, void* d_ws, size_t ws_size,
                              hipStream_t stream)
{
    const float* feat    = (const float*)d_in[0];
    const float* W_self  = (const float*)d_in[1];
    const float* b_self  = (const float*)d_in[2];
    const float* W_neigh = (const float*)d_in[3];
    const float* b_neigh = (const float*)d_in[4];
    const int*   src_idx = (const int*)d_in[5];
    const int*   dst_idx = (const int*)d_in[6];
    const int n_edges = in_sizes[5];

    float* h_neigh = (float*)d_ws;   // N_DST * D floats = 32 MB

    neigh_kernel<<<N_DST, 128, 0, stream>>>(feat, src_idx, dst_idx, n_edges, h_neigh);

    gemm_kernel<<<N_DST / TM, 256, 0, stream>>>(
        feat, h_neigh, W_self, W_neigh, b_self, b_neigh, (float*)d_out);
}

// Round 2
// 170.725 us; speedup vs baseline: 1.7836x; 1.7836x over previous
//
#include <hip/hip_runtime.h>
#include <hip/hip_bf16.h>

#define N_SRC   131072
#define N_DST   65536
#define D       128      // D_IN == D_OUT == 128

typedef __bf16 bf16x8 __attribute__((ext_vector_type(8)));
typedef __bf16 bf16x4 __attribute__((ext_vector_type(4)));
typedef float  f32x4  __attribute__((ext_vector_type(4)));

// ---------------------------------------------------------------------------
// Kernel A: sorted dst_idx -> CSR row offsets. row_start[r] = first edge with
// dst >= r; row_start[N_DST] = n_edges. Edge-parallel, coalesced, no atomics.
// ---------------------------------------------------------------------------
__global__ __launch_bounds__(256) void boundaries_kernel(
    const int* __restrict__ dst, int n_edges, int* __restrict__ row_start)
{
    const int e = blockIdx.x * 256 + threadIdx.x;
    if (e >= n_edges) return;
    const int d    = dst[e];
    const int prev = (e == 0) ? -1 : dst[e - 1];
    for (int r = prev + 1; r <= d; ++r) row_start[r] = e;
    if (e == n_edges - 1) {
        for (int r = d + 1; r <= N_DST; ++r) row_start[r] = n_edges;
    }
}

// ---------------------------------------------------------------------------
// Kernel B: W (fp32, K x N row-major) -> Wt (bf16, N x K row-major) so that
// MFMA B-fragments are contiguous 16B loads. Tiny (64 KB total).
// ---------------------------------------------------------------------------
__global__ __launch_bounds__(128) void prep_w_kernel(
    const float* __restrict__ W_self, const float* __restrict__ W_neigh,
    __bf16* __restrict__ Wt_self, __bf16* __restrict__ Wt_neigh)
{
    const int k = blockIdx.x;      // 0..127
    const int n = threadIdx.x;     // 0..127
    Wt_self [n * D + k] = (__bf16)W_self [k * D + n];
    Wt_neigh[n * D + k] = (__bf16)W_neigh[k * D + n];
}

// ---------------------------------------------------------------------------
// Kernel C: neighbor mean. 32-lane group per dst row; lane handles 4 cols via
// float4 loads (512 B per row access). Edge loop unrolled x4 for MLP.
// Output written as bf16 (halves write traffic + GEMM re-read traffic).
// ---------------------------------------------------------------------------
__global__ __launch_bounds__(256) void neigh_kernel(
    const float* __restrict__ feat,
    const int*   __restrict__ src,
    const int*   __restrict__ row_start,
    __bf16*      __restrict__ h_neigh)
{
    const int g    = threadIdx.x >> 5;        // group 0..7
    const int lane = threadIdx.x & 31;
    const int row  = blockIdx.x * 8 + g;
    const int s0   = row_start[row];
    const int s1   = row_start[row + 1];

    float ax = 0.f, ay = 0.f, az = 0.f, aw = 0.f;
    const int co = lane * 4;

    int e = s0;
    for (; e + 4 <= s1; e += 4) {
        const int ia = src[e + 0];
        const int ib = src[e + 1];
        const int ic = src[e + 2];
        const int id = src[e + 3];
        const float4 va = *(const float4*)&feat[(size_t)ia * D + co];
        const float4 vb = *(const float4*)&feat[(size_t)ib * D + co];
        const float4 vc = *(const float4*)&feat[(size_t)ic * D + co];
        const float4 vd = *(const float4*)&feat[(size_t)id * D + co];
        ax += (va.x + vb.x) + (vc.x + vd.x);
        ay += (va.y + vb.y) + (vc.y + vd.y);
        az += (va.z + vb.z) + (vc.z + vd.z);
        aw += (va.w + vb.w) + (vc.w + vd.w);
    }
    for (; e < s1; ++e) {
        const int s = src[e];
        const float4 v = *(const float4*)&feat[(size_t)s * D + co];
        ax += v.x; ay += v.y; az += v.z; aw += v.w;
    }

    const float inv = 1.0f / fmaxf((float)(s1 - s0), 1.0f);
    bf16x4 o;
    o[0] = (__bf16)(ax * inv);
    o[1] = (__bf16)(ay * inv);
    o[2] = (__bf16)(az * inv);
    o[3] = (__bf16)(aw * inv);
    *(bf16x4*)&h_neigh[(size_t)row * D + co] = o;
}

// ---------------------------------------------------------------------------
// Kernel D: out = feat[:N_DST] @ W_self + h_neigh @ W_neigh + (b_self+b_neigh)
// MFMA bf16 16x16x32, fp32 accumulate. No LDS, no barriers.
// Block = 256 threads = 4 waves; wave w covers rows [blk*128 + w*32, +32)
// (2 row-reps of 16), all 128 cols (8 n-blocks of 16).
// Fragment layouts (HW-verified):
//   A: lane holds A[m = lane&15][k = (lane>>4)*8 + j], j=0..7
//   B: lane holds B[k = (lane>>4)*8 + j][n = lane&15]    (from Wt[n][k])
//   C/D: col = lane&15, row = (lane>>4)*4 + reg
// ---------------------------------------------------------------------------
#define MREP 2

__global__ __launch_bounds__(256) void gemm_kernel(
    const float*  __restrict__ feat,      // fp32, first N_DST rows used
    const __bf16* __restrict__ h_neigh,   // bf16 N_DST x D
    const __bf16* __restrict__ Wt_self,   // bf16 [n][k]
    const __bf16* __restrict__ Wt_neigh,  // bf16 [n][k]
    const float*  __restrict__ b_self,
    const float*  __restrict__ b_neigh,
    float*        __restrict__ out)
{
    const int t    = threadIdx.x;
    const int w    = t >> 6;          // wave 0..3
    const int l    = t & 63;
    const int m16  = l & 15;
    const int quad = l >> 4;          // 0..3
    const int kb   = quad * 8;
    const int rowbase = blockIdx.x * (64 * MREP) + w * (16 * MREP);

    f32x4 acc[MREP][8];
    #pragma unroll
    for (int rp = 0; rp < MREP; ++rp)
        #pragma unroll
        for (int nb = 0; nb < 8; ++nb)
            acc[rp][nb] = (f32x4){0.f, 0.f, 0.f, 0.f};

    // ---- phase 0: A = feat (fp32 -> bf16 in-register) --------------------
    #pragma unroll
    for (int ks = 0; ks < 4; ++ks) {
        bf16x8 afrag[MREP];
        #pragma unroll
        for (int rp = 0; rp < MREP; ++rp) {
            const float* ap = &feat[(size_t)(rowbase + rp * 16 + m16) * D + ks * 32 + kb];
            const float4 a0 = *(const float4*)ap;
            const float4 a1 = *(const float4*)(ap + 4);
            afrag[rp][0] = (__bf16)a0.x; afrag[rp][1] = (__bf16)a0.y;
            afrag[rp][2] = (__bf16)a0.z; afrag[rp][3] = (__bf16)a0.w;
            afrag[rp][4] = (__bf16)a1.x; afrag[rp][5] = (__bf16)a1.y;
            afrag[rp][6] = (__bf16)a1.z; afrag[rp][7] = (__bf16)a1.w;
        }
        #pragma unroll
        for (int nb = 0; nb < 8; ++nb) {
            const bf16x8 bfrag = *(const bf16x8*)&Wt_self[(size_t)(nb * 16 + m16) * D + ks * 32 + kb];
            #pragma unroll
            for (int rp = 0; rp < MREP; ++rp)
                acc[rp][nb] = __builtin_amdgcn_mfma_f32_16x16x32_bf16(
                    afrag[rp], bfrag, acc[rp][nb], 0, 0, 0);
        }
    }

    // ---- phase 1: A = h_neigh (bf16 direct) ------------------------------
    #pragma unroll
    for (int ks = 0; ks < 4; ++ks) {
        bf16x8 afrag[MREP];
        #pragma unroll
        for (int rp = 0; rp < MREP; ++rp)
            afrag[rp] = *(const bf16x8*)&h_neigh[(size_t)(rowbase + rp * 16 + m16) * D + ks * 32 + kb];
        #pragma unroll
        for (int nb = 0; nb < 8; ++nb) {
            const bf16x8 bfrag = *(const bf16x8*)&Wt_neigh[(size_t)(nb * 16 + m16) * D + ks * 32 + kb];
            #pragma unroll
            for (int rp = 0; rp < MREP; ++rp)
                acc[rp][nb] = __builtin_amdgcn_mfma_f32_16x16x32_bf16(
                    afrag[rp], bfrag, acc[rp][nb], 0, 0, 0);
        }
    }

    // ---- epilogue --------------------------------------------------------
    #pragma unroll
    for (int nb = 0; nb < 8; ++nb) {
        const int col = nb * 16 + m16;
        const float bias = b_self[col] + b_neigh[col];
        #pragma unroll
        for (int rp = 0; rp < MREP; ++rp) {
            const int orow0 = rowbase + rp * 16 + quad * 4;
            #pragma unroll
            for (int r = 0; r < 4; ++r)
                out[(size_t)(orow0 + r) * D + col] = acc[rp][nb][r] + bias;
        }
    }
}

// ---------------------------------------------------------------------------
extern "C" void kernel_launch(void* const* d_in, const int* in_sizes, int n_in,
                              void* d_out, int out_size, void* d_ws, size_t ws_size,
                              hipStream_t stream)
{
    const float* feat    = (const float*)d_in[0];
    const float* W_self  = (const float*)d_in[1];
    const float* b_self  = (const float*)d_in[2];
    const float* W_neigh = (const float*)d_in[3];
    const float* b_neigh = (const float*)d_in[4];
    const int*   src_idx = (const int*)d_in[5];
    const int*   dst_idx = (const int*)d_in[6];
    const int n_edges = in_sizes[5];

    // workspace layout
    char* ws = (char*)d_ws;
    __bf16* h_neigh  = (__bf16*)ws;                                   // 16 MB
    int*    row_start = (int*)(ws + (size_t)N_DST * D * 2);           // 256 KB+
    __bf16* Wt_self  = (__bf16*)(ws + (size_t)N_DST * D * 2 + 262400);
    __bf16* Wt_neigh = Wt_self + D * D;

    boundaries_kernel<<<(n_edges + 255) / 256, 256, 0, stream>>>(dst_idx, n_edges, row_start);
    prep_w_kernel<<<D, D, 0, stream>>>(W_self, W_neigh, Wt_self, Wt_neigh);
    neigh_kernel<<<N_DST / 8, 256, 0, stream>>>(feat, src_idx, row_start, h_neigh);
    gemm_kernel<<<N_DST / (64 * MREP), 256, 0, stream>>>(
        feat, h_neigh, Wt_self, Wt_neigh, b_self, b_neigh, (float*)d_out);
}

// Round 3
// 166.845 us; speedup vs baseline: 1.8250x; 1.0233x over previous
//
#include <hip/hip_runtime.h>
#include <hip/hip_bf16.h>

#define N_SRC   131072
#define N_DST   65536
#define D       128      // D_IN == D_OUT == 128

typedef __bf16 bf16x8 __attribute__((ext_vector_type(8)));
typedef float  f32x4  __attribute__((ext_vector_type(4)));

#define CONV_BLOCKS 8192   // (N_SRC*D) / (256 threads * 8 elems) = 8192
#define W_BLOCKS    64     // 64*256 = 16384 = D*D elements (each thread does both W's)

// ---------------------------------------------------------------------------
// Kernel 1 (fused prep): role-split grid.
//  blocks [0, CONV_BLOCKS)                : feat fp32 -> bf16 (streaming)
//  blocks [CONV_BLOCKS, CONV+n_bnd)       : sorted dst -> CSR row_start
//  blocks [CONV+n_bnd, CONV+n_bnd+64)     : W fp32 [k][n] -> Wt bf16 [n][k]
// ---------------------------------------------------------------------------
__global__ __launch_bounds__(256) void prep_kernel(
    const float* __restrict__ feat,
    const int*   __restrict__ dst, int n_edges, int n_bnd_blocks,
    const float* __restrict__ W_self, const float* __restrict__ W_neigh,
    __bf16* __restrict__ feat_bf,
    int*    __restrict__ row_start,
    __bf16* __restrict__ Wt_self, __bf16* __restrict__ Wt_neigh)
{
    const int b = blockIdx.x;
    const int t = threadIdx.x;

    if (b < CONV_BLOCKS) {
        const size_t i0 = ((size_t)b * 256 + t) * 8;
        const float4 a0 = *(const float4*)&feat[i0];
        const float4 a1 = *(const float4*)&feat[i0 + 4];
        bf16x8 o;
        o[0] = (__bf16)a0.x; o[1] = (__bf16)a0.y; o[2] = (__bf16)a0.z; o[3] = (__bf16)a0.w;
        o[4] = (__bf16)a1.x; o[5] = (__bf16)a1.y; o[6] = (__bf16)a1.z; o[7] = (__bf16)a1.w;
        *(bf16x8*)&feat_bf[i0] = o;
    } else if (b < CONV_BLOCKS + n_bnd_blocks) {
        const int e = (b - CONV_BLOCKS) * 256 + t;
        if (e < n_edges) {
            const int d    = dst[e];
            const int prev = (e == 0) ? -1 : dst[e - 1];
            for (int r = prev + 1; r <= d; ++r) row_start[r] = e;
            if (e == n_edges - 1)
                for (int r = d + 1; r <= N_DST; ++r) row_start[r] = n_edges;
        }
    } else {
        const int wb  = b - CONV_BLOCKS - n_bnd_blocks;  // 0..63
        const int idx = wb * 256 + t;                    // 0..16383
        const int k = idx >> 7, n = idx & 127;
        Wt_self [n * D + k] = (__bf16)W_self [k * D + n];
        Wt_neigh[n * D + k] = (__bf16)W_neigh[k * D + n];
    }
}

// ---------------------------------------------------------------------------
// Kernel 2: neighbor mean over bf16 feat (L3-resident, 32 MB).
// 16-lane group per dst row; lane loads bf16x8 (16 B) -> 256 B per row in one
// segment. Edge loop unrolled x4 (4 KB in flight per group incl. 4 groups/wave).
// fp32 accumulate, bf16 output.
// ---------------------------------------------------------------------------
__global__ __launch_bounds__(256) void neigh_kernel(
    const __bf16* __restrict__ feat_bf,
    const int*    __restrict__ src,
    const int*    __restrict__ row_start,
    __bf16*       __restrict__ h_neigh)
{
    const int g    = threadIdx.x >> 4;        // group 0..15
    const int lane = threadIdx.x & 15;
    const int row  = blockIdx.x * 16 + g;
    const int s0   = row_start[row];
    const int s1   = row_start[row + 1];
    const int co   = lane * 8;

    float acc[8] = {0.f, 0.f, 0.f, 0.f, 0.f, 0.f, 0.f, 0.f};

    int e = s0;
    for (; e + 4 <= s1; e += 4) {
        const int sa = src[e + 0];
        const int sb = src[e + 1];
        const int sc = src[e + 2];
        const int sd = src[e + 3];
        const bf16x8 va = *(const bf16x8*)&feat_bf[(size_t)sa * D + co];
        const bf16x8 vb = *(const bf16x8*)&feat_bf[(size_t)sb * D + co];
        const bf16x8 vc = *(const bf16x8*)&feat_bf[(size_t)sc * D + co];
        const bf16x8 vd = *(const bf16x8*)&feat_bf[(size_t)sd * D + co];
        #pragma unroll
        for (int j = 0; j < 8; ++j)
            acc[j] += ((float)va[j] + (float)vb[j]) + ((float)vc[j] + (float)vd[j]);
    }
    for (; e < s1; ++e) {
        const int s = src[e];
        const bf16x8 v = *(const bf16x8*)&feat_bf[(size_t)s * D + co];
        #pragma unroll
        for (int j = 0; j < 8; ++j) acc[j] += (float)v[j];
    }

    const float inv = 1.0f / fmaxf((float)(s1 - s0), 1.0f);
    bf16x8 o;
    #pragma unroll
    for (int j = 0; j < 8; ++j) o[j] = (__bf16)(acc[j] * inv);
    *(bf16x8*)&h_neigh[(size_t)row * D + co] = o;
}

// ---------------------------------------------------------------------------
// Kernel 3: out = feat_bf[:N_DST] @ W_self + h_neigh @ W_neigh + biases.
// MFMA bf16 16x16x32, fp32 accumulate. No LDS, no barriers.
// Fragment layouts (HW-verified, passed rounds 1-2):
//   A: lane holds A[m = lane&15][k = (lane>>4)*8 + j]
//   B: lane holds B[k = (lane>>4)*8 + j][n = lane&15]   (from Wt[n][k])
//   C/D: col = lane&15, row = (lane>>4)*4 + reg
// ---------------------------------------------------------------------------
#define MREP 2

__global__ __launch_bounds__(256) void gemm_kernel(
    const __bf16* __restrict__ feat_bf,   // bf16, first N_DST rows used
    const __bf16* __restrict__ h_neigh,   // bf16 N_DST x D
    const __bf16* __restrict__ Wt_self,   // bf16 [n][k]
    const __bf16* __restrict__ Wt_neigh,  // bf16 [n][k]
    const float*  __restrict__ b_self,
    const float*  __restrict__ b_neigh,
    float*        __restrict__ out)
{
    const int t    = threadIdx.x;
    const int w    = t >> 6;          // wave 0..3
    const int l    = t & 63;
    const int m16  = l & 15;
    const int quad = l >> 4;          // 0..3
    const int kb   = quad * 8;
    const int rowbase = blockIdx.x * (64 * MREP) + w * (16 * MREP);

    f32x4 acc[MREP][8];
    #pragma unroll
    for (int rp = 0; rp < MREP; ++rp)
        #pragma unroll
        for (int nb = 0; nb < 8; ++nb)
            acc[rp][nb] = (f32x4){0.f, 0.f, 0.f, 0.f};

    const __bf16* __restrict__ Aptr[2] = {feat_bf, h_neigh};
    const __bf16* __restrict__ Wptr[2] = {Wt_self, Wt_neigh};

    #pragma unroll
    for (int p = 0; p < 2; ++p) {
        const __bf16* __restrict__ A = Aptr[p];
        const __bf16* __restrict__ W = Wptr[p];
        #pragma unroll
        for (int ks = 0; ks < 4; ++ks) {
            bf16x8 afrag[MREP];
            #pragma unroll
            for (int rp = 0; rp < MREP; ++rp)
                afrag[rp] = *(const bf16x8*)&A[(size_t)(rowbase + rp * 16 + m16) * D + ks * 32 + kb];
            #pragma unroll
            for (int nb = 0; nb < 8; ++nb) {
                const bf16x8 bfrag = *(const bf16x8*)&W[(size_t)(nb * 16 + m16) * D + ks * 32 + kb];
                #pragma unroll
                for (int rp = 0; rp < MREP; ++rp)
                    acc[rp][nb] = __builtin_amdgcn_mfma_f32_16x16x32_bf16(
                        afrag[rp], bfrag, acc[rp][nb], 0, 0, 0);
            }
        }
    }

    // epilogue
    #pragma unroll
    for (int nb = 0; nb < 8; ++nb) {
        const int col  = nb * 16 + m16;
        const float bias = b_self[col] + b_neigh[col];
        #pragma unroll
        for (int rp = 0; rp < MREP; ++rp) {
            const int orow0 = rowbase + rp * 16 + quad * 4;
            #pragma unroll
            for (int r = 0; r < 4; ++r)
                out[(size_t)(orow0 + r) * D + col] = acc[rp][nb][r] + bias;
        }
    }
}

// ---------------------------------------------------------------------------
extern "C" void kernel_launch(void* const* d_in, const int* in_sizes, int n_in,
                              void* d_out, int out_size, void* d_ws, size_t ws_size,
                              hipStream_t stream)
{
    const float* feat    = (const float*)d_in[0];
    const float* W_self  = (const float*)d_in[1];
    const float* b_self  = (const float*)d_in[2];
    const float* W_neigh = (const float*)d_in[3];
    const float* b_neigh = (const float*)d_in[4];
    const int*   src_idx = (const int*)d_in[5];
    const int*   dst_idx = (const int*)d_in[6];
    const int n_edges = in_sizes[5];

    // workspace layout
    char* ws = (char*)d_ws;
    __bf16* feat_bf  = (__bf16*)ws;                                  // 32 MB
    __bf16* h_neigh  = feat_bf + (size_t)N_SRC * D;                  // 16 MB
    int*    row_start = (int*)(h_neigh + (size_t)N_DST * D);         // 256 KB
    __bf16* Wt_self  = (__bf16*)(row_start + N_DST + 16);
    __bf16* Wt_neigh = Wt_self + D * D;

    const int n_bnd = (n_edges + 255) / 256;
    prep_kernel<<<CONV_BLOCKS + n_bnd + W_BLOCKS, 256, 0, stream>>>(
        feat, dst_idx, n_edges, n_bnd, W_self, W_neigh,
        feat_bf, row_start, Wt_self, Wt_neigh);

    neigh_kernel<<<N_DST / 16, 256, 0, stream>>>(feat_bf, src_idx, row_start, h_neigh);

    gemm_kernel<<<N_DST / (64 * MREP), 256, 0, stream>>>(
        feat_bf, h_neigh, Wt_self, Wt_neigh, b_self, b_neigh, (float*)d_out);
}

// Round 4
// 165.270 us; speedup vs baseline: 1.8424x; 1.0095x over previous
//
#include <hip/hip_runtime.h>
#include <hip/hip_bf16.h>

#define N_SRC   131072
#define N_DST   65536
#define D       128      // D_IN == D_OUT == 128

typedef __bf16 bf16x8 __attribute__((ext_vector_type(8)));
typedef float  f32x4  __attribute__((ext_vector_type(4)));

#define CONV_BLOCKS 8192   // (N_SRC*D) / (256 threads * 8 elems) = 8192
#define W_BLOCKS    64     // 64*256 = 16384 = D*D elements

// ---------------------------------------------------------------------------
// Kernel 1 (fused prep): role-split grid.
//  blocks [0, CONV_BLOCKS)                : feat fp32 -> bf16 (streaming)
//  blocks [CONV_BLOCKS, CONV+n_bnd)       : sorted dst -> CSR row_start
//  blocks [CONV+n_bnd, CONV+n_bnd+64)     : W fp32 [k][n] -> Wt bf16 [n][k]
// ---------------------------------------------------------------------------
__global__ __launch_bounds__(256) void prep_kernel(
    const float* __restrict__ feat,
    const int*   __restrict__ dst, int n_edges, int n_bnd_blocks,
    const float* __restrict__ W_self, const float* __restrict__ W_neigh,
    __bf16* __restrict__ feat_bf,
    int*    __restrict__ row_start,
    __bf16* __restrict__ Wt_self, __bf16* __restrict__ Wt_neigh)
{
    const int b = blockIdx.x;
    const int t = threadIdx.x;

    if (b < CONV_BLOCKS) {
        const size_t i0 = ((size_t)b * 256 + t) * 8;
        const float4 a0 = *(const float4*)&feat[i0];
        const float4 a1 = *(const float4*)&feat[i0 + 4];
        bf16x8 o;
        o[0] = (__bf16)a0.x; o[1] = (__bf16)a0.y; o[2] = (__bf16)a0.z; o[3] = (__bf16)a0.w;
        o[4] = (__bf16)a1.x; o[5] = (__bf16)a1.y; o[6] = (__bf16)a1.z; o[7] = (__bf16)a1.w;
        *(bf16x8*)&feat_bf[i0] = o;
    } else if (b < CONV_BLOCKS + n_bnd_blocks) {
        const int e = (b - CONV_BLOCKS) * 256 + t;
        if (e < n_edges) {
            const int d    = dst[e];
            const int prev = (e == 0) ? -1 : dst[e - 1];
            for (int r = prev + 1; r <= d; ++r) row_start[r] = e;
            if (e == n_edges - 1)
                for (int r = d + 1; r <= N_DST; ++r) row_start[r] = n_edges;
        }
    } else {
        const int wb  = b - CONV_BLOCKS - n_bnd_blocks;  // 0..63
        const int idx = wb * 256 + t;                    // 0..16383
        const int k = idx >> 7, n = idx & 127;
        Wt_self [n * D + k] = (__bf16)W_self [k * D + n];
        Wt_neigh[n * D + k] = (__bf16)W_neigh[k * D + n];
    }
}

// ---------------------------------------------------------------------------
// Kernel 2: neighbor mean over bf16 feat (L3-resident, 32 MB).
// 16-lane group per dst row; lane covers 8 cols (16 B). Edge loop is a
// predicated unroll-8: every chunk issues 8 independent 16 B loads with
// clamped indices, accumulation masked by validity (mask-FMA). No remainder
// loop -> no dependent serial tail; 8 loads in flight per group at all times.
// ---------------------------------------------------------------------------
__global__ __launch_bounds__(256) void neigh_kernel(
    const __bf16* __restrict__ feat_bf,
    const int*    __restrict__ src,
    const int*    __restrict__ row_start,
    __bf16*       __restrict__ h_neigh)
{
    const int g    = threadIdx.x >> 4;        // group 0..15
    const int lane = threadIdx.x & 15;
    const int row  = blockIdx.x * 16 + g;
    const int s0   = row_start[row];
    const int s1   = row_start[row + 1];
    const int co   = lane * 8;

    float acc[8] = {0.f, 0.f, 0.f, 0.f, 0.f, 0.f, 0.f, 0.f};

    for (int base = s0; base < s1; base += 8) {
        // issue 8 independent index loads (clamped), then 8 feature loads
        int idx[8];
        #pragma unroll
        for (int j = 0; j < 8; ++j) {
            const int e = base + j;
            idx[j] = src[e < s1 ? e : s1 - 1];
        }
        bf16x8 v[8];
        #pragma unroll
        for (int j = 0; j < 8; ++j)
            v[j] = *(const bf16x8*)&feat_bf[(size_t)idx[j] * D + co];
        #pragma unroll
        for (int j = 0; j < 8; ++j) {
            const float m = (base + j < s1) ? 1.0f : 0.0f;
            #pragma unroll
            for (int c = 0; c < 8; ++c)
                acc[c] = fmaf(m, (float)v[j][c], acc[c]);
        }
    }

    const float inv = 1.0f / fmaxf((float)(s1 - s0), 1.0f);
    bf16x8 o;
    #pragma unroll
    for (int c = 0; c < 8; ++c) o[c] = (__bf16)(acc[c] * inv);
    *(bf16x8*)&h_neigh[(size_t)row * D + co] = o;
}

// ---------------------------------------------------------------------------
// Kernel 3: out = feat_bf[:N_DST] @ W_self + h_neigh @ W_neigh + biases.
// MFMA bf16 16x16x32, fp32 accumulate. No LDS, no barriers.
// Fragment layouts (HW-verified, passed rounds 1-3):
//   A: lane holds A[m = lane&15][k = (lane>>4)*8 + j]
//   B: lane holds B[k = (lane>>4)*8 + j][n = lane&15]   (from Wt[n][k])
//   C/D: col = lane&15, row = (lane>>4)*4 + reg
// ---------------------------------------------------------------------------
#define MREP 2

__global__ __launch_bounds__(256) void gemm_kernel(
    const __bf16* __restrict__ feat_bf,   // bf16, first N_DST rows used
    const __bf16* __restrict__ h_neigh,   // bf16 N_DST x D
    const __bf16* __restrict__ Wt_self,   // bf16 [n][k]
    const __bf16* __restrict__ Wt_neigh,  // bf16 [n][k]
    const float*  __restrict__ b_self,
    const float*  __restrict__ b_neigh,
    float*        __restrict__ out)
{
    const int t    = threadIdx.x;
    const int w    = t >> 6;          // wave 0..3
    const int l    = t & 63;
    const int m16  = l & 15;
    const int quad = l >> 4;          // 0..3
    const int kb   = quad * 8;
    const int rowbase = blockIdx.x * (64 * MREP) + w * (16 * MREP);

    f32x4 acc[MREP][8];
    #pragma unroll
    for (int rp = 0; rp < MREP; ++rp)
        #pragma unroll
        for (int nb = 0; nb < 8; ++nb)
            acc[rp][nb] = (f32x4){0.f, 0.f, 0.f, 0.f};

    const __bf16* __restrict__ Aptr[2] = {feat_bf, h_neigh};
    const __bf16* __restrict__ Wptr[2] = {Wt_self, Wt_neigh};

    #pragma unroll
    for (int p = 0; p < 2; ++p) {
        const __bf16* __restrict__ A = Aptr[p];
        const __bf16* __restrict__ W = Wptr[p];
        #pragma unroll
        for (int ks = 0; ks < 4; ++ks) {
            bf16x8 afrag[MREP];
            #pragma unroll
            for (int rp = 0; rp < MREP; ++rp)
                afrag[rp] = *(const bf16x8*)&A[(size_t)(rowbase + rp * 16 + m16) * D + ks * 32 + kb];
            #pragma unroll
            for (int nb = 0; nb < 8; ++nb) {
                const bf16x8 bfrag = *(const bf16x8*)&W[(size_t)(nb * 16 + m16) * D + ks * 32 + kb];
                #pragma unroll
                for (int rp = 0; rp < MREP; ++rp)
                    acc[rp][nb] = __builtin_amdgcn_mfma_f32_16x16x32_bf16(
                        afrag[rp], bfrag, acc[rp][nb], 0, 0, 0);
            }
        }
    }

    // epilogue
    #pragma unroll
    for (int nb = 0; nb < 8; ++nb) {
        const int col  = nb * 16 + m16;
        const float bias = b_self[col] + b_neigh[col];
        #pragma unroll
        for (int rp = 0; rp < MREP; ++rp) {
            const int orow0 = rowbase + rp * 16 + quad * 4;
            #pragma unroll
            for (int r = 0; r < 4; ++r)
                out[(size_t)(orow0 + r) * D + col] = acc[rp][nb][r] + bias;
        }
    }
}

// ---------------------------------------------------------------------------
extern "C" void kernel_launch(void* const* d_in, const int* in_sizes, int n_in,
                              void* d_out, int out_size, void* d_ws, size_t ws_size,
                              hipStream_t stream)
{
    const float* feat    = (const float*)d_in[0];
    const float* W_self  = (const float*)d_in[1];
    const float* b_self  = (const float*)d_in[2];
    const float* W_neigh = (const float*)d_in[3];
    const float* b_neigh = (const float*)d_in[4];
    const int*   src_idx = (const int*)d_in[5];
    const int*   dst_idx = (const int*)d_in[6];
    const int n_edges = in_sizes[5];

    // workspace layout
    char* ws = (char*)d_ws;
    __bf16* feat_bf  = (__bf16*)ws;                                  // 32 MB
    __bf16* h_neigh  = feat_bf + (size_t)N_SRC * D;                  // 16 MB
    int*    row_start = (int*)(h_neigh + (size_t)N_DST * D);         // 256 KB
    __bf16* Wt_self  = (__bf16*)(row_start + N_DST + 16);
    __bf16* Wt_neigh = Wt_self + D * D;

    const int n_bnd = (n_edges + 255) / 256;
    prep_kernel<<<CONV_BLOCKS + n_bnd + W_BLOCKS, 256, 0, stream>>>(
        feat, dst_idx, n_edges, n_bnd, W_self, W_neigh,
        feat_bf, row_start, Wt_self, Wt_neigh);

    neigh_kernel<<<N_DST / 16, 256, 0, stream>>>(feat_bf, src_idx, row_start, h_neigh);

    gemm_kernel<<<N_DST / (64 * MREP), 256, 0, stream>>>(
        feat_bf, h_neigh, Wt_self, Wt_neigh, b_self, b_neigh, (float*)d_out);
}